// Round 2
// baseline (375.640 us; speedup 1.0000x reference)
//
#include <hip/hip_runtime.h>
#include <type_traits>

#define DIN 1024
#define DIMM 1024
#define NH 16
#define HD 64
#define SEQ 2048
#define BATCH 2
#define MTOT (BATCH*SEQ)   // 4096
#define LDT 40             // LDS leading dim (32 + 8 pad) in elements
#define SCALE 0.125f       // 1/sqrt(64)

typedef __bf16 bf16;
typedef __bf16 bf16x8 __attribute__((ext_vector_type(8)));
typedef float f32x4 __attribute__((ext_vector_type(4)));

// Load 8 contiguous elements as bf16x8, converting from fp32 if needed.
template<typename T>
__device__ __forceinline__ bf16x8 ld8bf16(const T* __restrict__ p) {
  if constexpr (std::is_same<T, float>::value) {
    const f32x4* q = (const f32x4*)p;
    f32x4 a = q[0], b = q[1];
    bf16x8 r;
    r[0] = (bf16)a[0]; r[1] = (bf16)a[1]; r[2] = (bf16)a[2]; r[3] = (bf16)a[3];
    r[4] = (bf16)b[0]; r[5] = (bf16)b[1]; r[6] = (bf16)b[2]; r[7] = (bf16)b[3];
    return r;
  } else {
    return *(const bf16x8*)p;
  }
}

// ---------------- GEMM: C = A * W^T ----------------
// A: M x K row-major;  W: N x K row-major (torch Linear layout); C: M x N.
// Block = 256 thr (4 waves), tile 64x64, BK=32. Inputs converted to bf16 at
// LDS staging; accumulate fp32; store TC.
template<typename TA, typename TW, typename TC>
__device__ __forceinline__ void gemm_bt_body(const TA* __restrict__ A,
                                             const TW* __restrict__ W,
                                             TC* __restrict__ C,
                                             int M, int N, int K) {
  __shared__ bf16 As[64 * LDT];
  __shared__ bf16 Ws[64 * LDT];
  const int tid  = threadIdx.x;
  const int wave = tid >> 6;
  const int lane = tid & 63;
  const int mbase = blockIdx.y * 64;
  const int nbase = blockIdx.x * 64;
  const int lr = tid >> 2;          // staging row 0..63
  const int lc = (tid & 3) * 8;     // staging col {0,8,16,24}
  const int frow = lane & 15;       // fragment m/n index
  const int quad = lane >> 4;
  const int fk   = quad * 8;        // fragment k base

  f32x4 acc[4] = {};

  for (int k0 = 0; k0 < K; k0 += 32) {
    *(bf16x8*)&As[lr * LDT + lc] = ld8bf16(&A[(size_t)(mbase + lr) * K + k0 + lc]);
    *(bf16x8*)&Ws[lr * LDT + lc] = ld8bf16(&W[(size_t)(nbase + lr) * K + k0 + lc]);
    __syncthreads();
    bf16x8 af = *(const bf16x8*)&As[(wave * 16 + frow) * LDT + fk];
#pragma unroll
    for (int nt = 0; nt < 4; ++nt) {
      bf16x8 bfr = *(const bf16x8*)&Ws[(nt * 16 + frow) * LDT + fk];
      acc[nt] = __builtin_amdgcn_mfma_f32_16x16x32_bf16(af, bfr, acc[nt], 0, 0, 0);
    }
    __syncthreads();
  }
  const int crow = mbase + wave * 16 + quad * 4;
  const int ccol = nbase + frow;
#pragma unroll
  for (int nt = 0; nt < 4; ++nt)
#pragma unroll
    for (int rr = 0; rr < 4; ++rr) {
      if constexpr (std::is_same<TC, float>::value)
        C[(size_t)(crow + rr) * N + ccol + nt * 16] = acc[nt][rr];
      else
        C[(size_t)(crow + rr) * N + ccol + nt * 16] = (bf16)acc[nt][rr];
    }
}

__global__ __launch_bounds__(256) void qkv_gemm(const float* __restrict__ x,
                                                const float* __restrict__ wq,
                                                const float* __restrict__ wk,
                                                const float* __restrict__ wv,
                                                bf16* __restrict__ q,
                                                bf16* __restrict__ k,
                                                bf16* __restrict__ v) {
  const float* W = (blockIdx.z == 0) ? wq : (blockIdx.z == 1) ? wk : wv;
  bf16* C        = (blockIdx.z == 0) ? q  : (blockIdx.z == 1) ? k  : v;
  gemm_bt_body<float, float, bf16>(x, W, C, MTOT, DIMM, DIN);
}

__global__ __launch_bounds__(256) void proj_gemm(const bf16* __restrict__ A,
                                                 const float* __restrict__ W,
                                                 float* __restrict__ C) {
  gemm_bt_body<bf16, float, float>(A, W, C, MTOT, DIMM, DIMM);
}

// ---------------- Causal flash attention ----------------
// Q,K,V: (B*S, 1024) bf16, head h at cols [h*64, h*64+64).
// Block = 4 waves; wave handles one 16-row Q tile of one (b,h).
// Online softmax on raw scores; p = exp((s - m) * 1/8)  (mask-before-scale
// matches reference since -inf invariant under positive scale).
__global__ __launch_bounds__(256) void attn(const bf16* __restrict__ Q,
                                            const bf16* __restrict__ K,
                                            const bf16* __restrict__ V,
                                            bf16* __restrict__ O) {
  __shared__ bf16 Plds[4][16 * LDT];  // per-wave 16x32 P tile
  const int wave = threadIdx.x >> 6;
  const int lane = threadIdx.x & 63;
  const int lrow = lane & 15;
  const int quad = lane >> 4;
  const int nq = SEQ / 64;                 // q-chunks per (b,h)
  const int bh = blockIdx.x / nq;
  const int qc = blockIdx.x - bh * nq;
  const int b  = bh >> 4;
  const int h  = bh & 15;
  const int qbase = qc * 64 + wave * 16;

  const bf16* Qh = Q + (size_t)(b * SEQ) * DIMM + h * HD;
  const bf16* Kh = K + (size_t)(b * SEQ) * DIMM + h * HD;
  const bf16* Vh = V + (size_t)(b * SEQ) * DIMM + h * HD;

  // Q fragments (A-layout), d split 0..31 / 32..63
  bf16x8 qf0 = *(const bf16x8*)&Qh[(size_t)(qbase + lrow) * DIMM + quad * 8];
  bf16x8 qf1 = *(const bf16x8*)&Qh[(size_t)(qbase + lrow) * DIMM + 32 + quad * 8];

  float m_i[4], l_i[4];
  f32x4 o_acc[4] = {};
#pragma unroll
  for (int r = 0; r < 4; ++r) { m_i[r] = -1e30f; l_i[r] = 0.f; }

  const int ktiles = (qbase + 16 + 31) >> 5;  // causal: k <= qbase+15
  for (int kt = 0; kt < ktiles; ++kt) {
    const int kbase = kt * 32;
    // S = Q K^T : two 16x16 col-halves, contraction d=64 (2 MFMAs each)
    f32x4 s0 = {}, s1 = {};
    {
      bf16x8 kf;
      kf = *(const bf16x8*)&Kh[(size_t)(kbase + lrow) * DIMM + quad * 8];
      s0 = __builtin_amdgcn_mfma_f32_16x16x32_bf16(qf0, kf, s0, 0, 0, 0);
      kf = *(const bf16x8*)&Kh[(size_t)(kbase + lrow) * DIMM + 32 + quad * 8];
      s0 = __builtin_amdgcn_mfma_f32_16x16x32_bf16(qf1, kf, s0, 0, 0, 0);
      kf = *(const bf16x8*)&Kh[(size_t)(kbase + 16 + lrow) * DIMM + quad * 8];
      s1 = __builtin_amdgcn_mfma_f32_16x16x32_bf16(qf0, kf, s1, 0, 0, 0);
      kf = *(const bf16x8*)&Kh[(size_t)(kbase + 16 + lrow) * DIMM + 32 + quad * 8];
      s1 = __builtin_amdgcn_mfma_f32_16x16x32_bf16(qf1, kf, s1, 0, 0, 0);
    }
    // causal mask + online softmax (rows = quad*4+r, cols = lane&15)
    float p0[4], p1[4], al[4];
#pragma unroll
    for (int r = 0; r < 4; ++r) {
      const int qrow = qbase + quad * 4 + r;
      s0[r] = (kbase + lrow > qrow)      ? -1e30f : s0[r];
      s1[r] = (kbase + 16 + lrow > qrow) ? -1e30f : s1[r];
      float pm = fmaxf(s0[r], s1[r]);
      pm = fmaxf(pm, __shfl_xor(pm, 1));
      pm = fmaxf(pm, __shfl_xor(pm, 2));
      pm = fmaxf(pm, __shfl_xor(pm, 4));
      pm = fmaxf(pm, __shfl_xor(pm, 8));
      const float mn = fmaxf(m_i[r], pm);
      al[r] = __expf((m_i[r] - mn) * SCALE);
      p0[r] = __expf((s0[r] - mn) * SCALE);
      p1[r] = __expf((s1[r] - mn) * SCALE);
      float sum = p0[r] + p1[r];
      sum += __shfl_xor(sum, 1);
      sum += __shfl_xor(sum, 2);
      sum += __shfl_xor(sum, 4);
      sum += __shfl_xor(sum, 8);
      l_i[r] = l_i[r] * al[r] + sum;
      m_i[r] = mn;
    }
    // rescale O
#pragma unroll
    for (int dt = 0; dt < 4; ++dt)
#pragma unroll
      for (int r = 0; r < 4; ++r)
        o_acc[dt][r] *= al[r];
    // P: C-layout -> A-layout via per-wave LDS round trip
#pragma unroll
    for (int r = 0; r < 4; ++r) {
      Plds[wave][(quad * 4 + r) * LDT + lrow]      = (bf16)p0[r];
      Plds[wave][(quad * 4 + r) * LDT + 16 + lrow] = (bf16)p1[r];
    }
    asm volatile("s_waitcnt lgkmcnt(0)" ::: "memory");
    bf16x8 pf = *(const bf16x8*)&Plds[wave][lrow * LDT + quad * 8];
    // O += P V  (B-operand: V[k][d], transposed-gather scalar loads)
#pragma unroll
    for (int dt = 0; dt < 4; ++dt) {
      bf16x8 vf;
#pragma unroll
      for (int j = 0; j < 8; ++j)
        vf[j] = Vh[(size_t)(kbase + quad * 8 + j) * DIMM + dt * 16 + lrow];
      o_acc[dt] = __builtin_amdgcn_mfma_f32_16x16x32_bf16(pf, vf, o_acc[dt], 0, 0, 0);
    }
  }
  // epilogue: O / l, store ctx in (b, s, h*64+d) layout
  bf16* Oh = O + (size_t)(b * SEQ) * DIMM + h * HD;
#pragma unroll
  for (int dt = 0; dt < 4; ++dt)
#pragma unroll
    for (int r = 0; r < 4; ++r) {
      const float val = o_acc[dt][r] / l_i[r];
      Oh[(size_t)(qbase + quad * 4 + r) * DIMM + dt * 16 + lrow] = (bf16)val;
    }
}

// ---------------- launch ----------------
extern "C" void kernel_launch(void* const* d_in, const int* in_sizes, int n_in,
                              void* d_out, int out_size, void* d_ws, size_t ws_size,
                              hipStream_t stream) {
  const float* x  = (const float*)d_in[0];
  const float* wq = (const float*)d_in[1];
  const float* wk = (const float*)d_in[2];
  const float* wv = (const float*)d_in[3];
  const float* wo = (const float*)d_in[4];

  bf16* Q   = (bf16*)d_ws;
  bf16* K   = Q + (size_t)MTOT * DIMM;
  bf16* V   = K + (size_t)MTOT * DIMM;
  bf16* CTX = V + (size_t)MTOT * DIMM;
  float* out = (float*)d_out;

  dim3 blk(256);
  qkv_gemm<<<dim3(DIMM / 64, MTOT / 64, 3), blk, 0, stream>>>(x, wq, wk, wv, Q, K, V);
  attn<<<dim3(BATCH * NH * (SEQ / 64)), blk, 0, stream>>>(Q, K, V, CTX);
  proj_gemm<<<dim3(DIMM / 64, MTOT / 64), blk, 0, stream>>>(CTX, wo, out);
}